// Round 7
// baseline (2346.595 us; speedup 1.0000x reference)
//
#include <hip/hip_runtime.h>

// LSTM cell, B=8192, I=H=2048, fp32 in/out.
// fp16 hi/lo 3-term split GEMM on MFMA 32x32x16_f16.
// 256x256 tile, BK=64, 8 waves, 1 barrier/tile, all fragments register-live
// (no WAR reuse), chunk-permuted LDS layout: coalesced staging sources AND
// <=2-way-bank ds_read_b128 (no XOR swizzle needed).

#define PLANE 16777216   // 8192*2048 elements per [B,H] plane
#define T_TILES 192      // 6 segments x 32 K-tiles of 64

typedef _Float16 h8_t  __attribute__((ext_vector_type(8)));
typedef _Float16 h4_t  __attribute__((ext_vector_type(4)));
typedef float    f32x16 __attribute__((ext_vector_type(16)));

#define BARRIER() do { asm volatile("" ::: "memory"); \
                       __builtin_amdgcn_s_barrier();  \
                       asm volatile("" ::: "memory"); } while (0)

__device__ __forceinline__ float fast_sigmoid(float x) {
  return 1.0f / (1.0f + __expf(-x));
}
__device__ __forceinline__ float fast_tanh(float x) {
  float e = __expf(2.0f * x);
  return 1.0f - 2.0f / (e + 1.0f);
}

// ---------------- split: fp32 -> (hi, lo) fp16 ----------------
__global__ void split_kernel(const float* __restrict__ src,
                             _Float16* __restrict__ hi,
                             _Float16* __restrict__ lo, int n) {
  int idx = (blockIdx.x * blockDim.x + threadIdx.x) * 4;
  int stride = gridDim.x * blockDim.x * 4;
  for (int i = idx; i < n; i += stride) {
    float4 v = *reinterpret_cast<const float4*>(src + i);
    _Float16 h0 = (_Float16)v.x, h1 = (_Float16)v.y,
             h2 = (_Float16)v.z, h3 = (_Float16)v.w;
    h4_t hv = {h0, h1, h2, h3};
    h4_t lv = {(_Float16)(v.x - (float)h0), (_Float16)(v.y - (float)h1),
               (_Float16)(v.z - (float)h2), (_Float16)(v.w - (float)h3)};
    *reinterpret_cast<h4_t*>(hi + i) = hv;
    *reinterpret_cast<h4_t*>(lo + i) = lv;
  }
}

// ---------------- GEMM helpers ----------------
__device__ __forceinline__ void gload_lds16(const _Float16* g, _Float16* l) {
  __builtin_amdgcn_global_load_lds(
      (const __attribute__((address_space(1))) void*)g,
      (__attribute__((address_space(3))) void*)l, 16, 0, 0);
}

__device__ __forceinline__ const _Float16* segA(int kt,
    const _Float16* xH, const _Float16* xL,
    const _Float16* hH, const _Float16* hL) {
  int s = kt >> 5;
  return s == 0 ? xH : s == 1 ? xL : s == 2 ? xH : s == 3 ? hH : s == 4 ? hL : hH;
}
__device__ __forceinline__ const _Float16* segB(int kt,
    const _Float16* wH, const _Float16* wL,
    const _Float16* uH, const _Float16* uL) {
  int s = kt >> 5;
  return s < 2 ? wH : s == 2 ? wL : s < 5 ? uH : uL;
}
#define K0OF(kt) (((kt) & 31) << 6)

__global__ __launch_bounds__(512, 2) void gemm_gates_kernel(
    const _Float16* __restrict__ xH, const _Float16* __restrict__ xL,
    const _Float16* __restrict__ hH, const _Float16* __restrict__ hL,
    const _Float16* __restrict__ wH, const _Float16* __restrict__ wL,
    const _Float16* __restrict__ uH, const _Float16* __restrict__ uL,
    const float* __restrict__ bias,
    float* __restrict__ out, _Float16* __restrict__ o_ws) {
  // [buf][half(128 rows/cols)][16KB as chunk-permuted f16]
  // chunk p (16B) of (r in 0..127, cs in 0..7): p = (r>>3)*64 + cs*8 + (r&7)
  __shared__ _Float16 sA[2][2][8192];
  __shared__ _Float16 sB[2][2][8192];

  // XCD-aware swizzle: nwg = 1024 = 8 * 128.
  const int bid = blockIdx.x;
  const int wg = (bid & 7) * 128 + (bid >> 3);
  const int tm = wg >> 5;   // 0..31 (batch rows, 256 each)
  const int tn = wg & 31;   // 0..31 (output cols, 256 each)
  const int rowA = tm * 256;
  const int rowB = tn * 256;

  const int tid = threadIdx.x;
  const int w = tid >> 6;
  const int lane = tid & 63;
  const int wr = w >> 2;    // 0..1 : wave row half (128 rows)
  const int wc = w & 3;     // 0..3 : wave col quarter (64 cols)

  // ds_read per-lane constant (f16 elems): lane covers row (lane&31),
  // k-half (lane>>5) of a 32x16 operand tile.
  const int laneRd = ((lane & 31) >> 3) * 512 + (lane >> 5) * 64 + (lane & 7) * 8;
  const int bBase = (wc & 1) * 4096;  // col base within B half
  const int bHalf = wc >> 1;

  // Staging precompute: thread tid, call j stages LDS chunk p = j*512+tid
  // which holds global (row rj, k cs*8..cs*8+7).
  const int csS = (tid >> 3) & 7;
  unsigned aSrc[2][2], bSrc[2][2];   // [half][j] element offsets (k0=0)
  int ldsDest[2];
#pragma unroll
  for (int j = 0; j < 2; ++j) {
    const int rj = j * 64 + (tid >> 6) * 8 + (tid & 7);
    ldsDest[j] = (j * 512 + tid) * 8;
#pragma unroll
    for (int hh = 0; hh < 2; ++hh) {
      aSrc[hh][j] = (unsigned)((rowA + hh * 128 + rj) * 2048 + csS * 8);
      bSrc[hh][j] = (unsigned)((rowB + hh * 128 + rj) * 2048 + csS * 8);
    }
  }

#define STAGE_A(kt, hh) do {                                            \
    const _Float16* sg = segA((kt), xH, xL, hH, hL);                    \
    const unsigned k0 = (unsigned)K0OF(kt);                             \
    _Float16* d = &sA[(kt) & 1][hh][0];                                 \
    gload_lds16(sg + aSrc[hh][0] + k0, d + ldsDest[0]);                 \
    gload_lds16(sg + aSrc[hh][1] + k0, d + ldsDest[1]);                 \
  } while (0)
#define STAGE_B(kt, hh) do {                                            \
    const _Float16* sg = segB((kt), wH, wL, uH, uL);                    \
    const unsigned k0 = (unsigned)K0OF(kt);                             \
    _Float16* d = &sB[(kt) & 1][hh][0];                                 \
    gload_lds16(sg + bSrc[hh][0] + k0, d + ldsDest[0]);                 \
    gload_lds16(sg + bSrc[hh][1] + k0, d + ldsDest[1]);                 \
  } while (0)

  f32x16 acc[4][2];
#pragma unroll
  for (int mt = 0; mt < 4; ++mt)
#pragma unroll
    for (int nt = 0; nt < 2; ++nt)
#pragma unroll
      for (int r = 0; r < 16; ++r) acc[mt][nt][r] = 0.f;

  // Prologue: stage tile 0 fully (8 loads).
  STAGE_A(0, 0); STAGE_A(0, 1); STAGE_B(0, 0); STAGE_B(0, 1);

  h8_t aF[4][4];   // [mt][ks]  all live
  h8_t bF[2][4];   // [nt][ks]  all live

  for (int t = 0; t < T_TILES; ++t) {
    const _Float16* aP = &sA[t & 1][wr][0];
    const _Float16* bP = &sB[t & 1][bHalf][0];

    // All tile-t stages were issued >= one full tile ago; nothing else in
    // flight => vmcnt(0) is exact. BAR makes residency block-wide AND
    // guarantees every wave's buf-reads (tile t-1) completed (they passed
    // their lgkm waits before issuing MFMAs before arriving here).
    asm volatile("s_waitcnt vmcnt(0)" ::: "memory");
    BARRIER();

    const bool doStage = (t + 1 < T_TILES);
    if (doStage) STAGE_A(t + 1, 0);

    // ---- all 24 fragment reads (compiler interleaves lgkm waits) ----
#pragma unroll
    for (int ks = 0; ks < 4; ++ks)
#pragma unroll
      for (int mt = 0; mt < 4; ++mt)
        aF[mt][ks] = *reinterpret_cast<const h8_t*>(
            aP + mt * 2048 + ks * 128 + laneRd);
#pragma unroll
    for (int ks = 0; ks < 4; ++ks)
#pragma unroll
      for (int nt = 0; nt < 2; ++nt)
        bF[nt][ks] = *reinterpret_cast<const h8_t*>(
            bP + bBase + nt * 2048 + ks * 128 + laneRd);

    if (doStage) STAGE_A(t + 1, 1);

#define DO_KS(ks) do {                                                  \
    __builtin_amdgcn_s_setprio(1);                                      \
    _Pragma("unroll")                                                   \
    for (int mt = 0; mt < 4; ++mt)                                      \
      _Pragma("unroll")                                                 \
      for (int nt = 0; nt < 2; ++nt)                                    \
        acc[mt][nt] = __builtin_amdgcn_mfma_f32_32x32x16_f16(           \
            aF[mt][ks], bF[nt][ks], acc[mt][nt], 0, 0, 0);              \
    __builtin_amdgcn_s_setprio(0);                                      \
  } while (0)

    DO_KS(0);
    if (doStage) STAGE_B(t + 1, 0);
    DO_KS(1);
    if (doStage) STAGE_B(t + 1, 1);
    DO_KS(2);
    DO_KS(3);
#undef DO_KS
  }

  // ---- epilogue: activations, fused gate writes ----
  // C/D 32x32: col = lane&31, row = (reg&3) + 8*(reg>>2) + 4*(lane>>5).
  const int gate = tn >> 3;  // 8 n-tiles per gate
  const int rBase = tm * 256 + wr * 128 + 4 * (lane >> 5);
  const int cBase = tn * 256 + wc * 64 + (lane & 31);
#pragma unroll
  for (int nt = 0; nt < 2; ++nt) {
    const int col = cBase + nt * 32;
    const int hcol = col & 2047;
    const float bv = bias[col];
#pragma unroll
    for (int mt = 0; mt < 4; ++mt) {
#pragma unroll
      for (int reg = 0; reg < 16; ++reg) {
        const int row = rBase + mt * 32 + (reg & 3) + 8 * (reg >> 2);
        float v = acc[mt][nt][reg] + bv;
        size_t oidx = (size_t)row * 2048 + hcol;
        if (gate == 0)       out[(size_t)3 * PLANE + oidx] = fast_sigmoid(v);  // f_t
        else if (gate == 1)  out[(size_t)2 * PLANE + oidx] = fast_sigmoid(v);  // i_t
        else if (gate == 2)  out[(size_t)4 * PLANE + oidx] = fast_tanh(v);     // C~_t
        else                 o_ws[oidx] = (_Float16)fast_sigmoid(v);           // o_t
      }
    }
  }
}

// ---------------- final: C_t and h_t ----------------
__global__ void final_kernel(const float* __restrict__ outr,
                             const float* __restrict__ C_prev,
                             const _Float16* __restrict__ o_ws,
                             float* __restrict__ out) {
  const float* iP = outr + (size_t)2 * PLANE;
  const float* fP = outr + (size_t)3 * PLANE;
  const float* cP = outr + (size_t)4 * PLANE;
  int idx = (blockIdx.x * blockDim.x + threadIdx.x) * 4;
  int stride = gridDim.x * blockDim.x * 4;
  for (int i = idx; i < PLANE; i += stride) {
    float4 fv = *reinterpret_cast<const float4*>(fP + i);
    float4 iv = *reinterpret_cast<const float4*>(iP + i);
    float4 cv = *reinterpret_cast<const float4*>(cP + i);
    float4 cp = *reinterpret_cast<const float4*>(C_prev + i);
    h4_t ov = *reinterpret_cast<const h4_t*>(o_ws + i);
    float4 C, H;
    C.x = fv.x * cp.x + iv.x * cv.x;
    C.y = fv.y * cp.y + iv.y * cv.y;
    C.z = fv.z * cp.z + iv.z * cv.z;
    C.w = fv.w * cp.w + iv.w * cv.w;
    H.x = (float)ov.x * fast_tanh(C.x);
    H.y = (float)ov.y * fast_tanh(C.y);
    H.z = (float)ov.z * fast_tanh(C.z);
    H.w = (float)ov.w * fast_tanh(C.w);
    *reinterpret_cast<float4*>(out + (size_t)PLANE + i) = C;  // C_t
    *reinterpret_cast<float4*>(out + i) = H;                  // h_t
  }
}

extern "C" void kernel_launch(void* const* d_in, const int* in_sizes, int n_in,
                              void* d_out, int out_size, void* d_ws, size_t ws_size,
                              hipStream_t stream) {
  const float* x  = (const float*)d_in[0];
  const float* hp = (const float*)d_in[1];
  const float* Cp = (const float*)d_in[2];
  const float* W  = (const float*)d_in[3];
  const float* U  = (const float*)d_in[4];
  const float* b  = (const float*)d_in[5];
  float* out = (float*)d_out;

  _Float16* ws = (_Float16*)d_ws;
  _Float16* xh = ws;
  _Float16* xl = xh + PLANE;
  _Float16* hh = xl + PLANE;
  _Float16* hl = hh + PLANE;
  _Float16* Wh = hl + PLANE;
  _Float16* Wl = Wh + PLANE;
  _Float16* Uh = Wl + PLANE;
  _Float16* Ul = Uh + PLANE;
  _Float16* o_ws = Ul + PLANE;  // total ws use: 9 * 32 MiB = 288 MiB

  dim3 blk(256);
  split_kernel<<<dim3(2048), blk, 0, stream>>>(x, xh, xl, PLANE);
  split_kernel<<<dim3(2048), blk, 0, stream>>>(hp, hh, hl, PLANE);
  split_kernel<<<dim3(2048), blk, 0, stream>>>(W, Wh, Wl, PLANE);
  split_kernel<<<dim3(2048), blk, 0, stream>>>(U, Uh, Ul, PLANE);
  gemm_gates_kernel<<<dim3(1024), dim3(512), 0, stream>>>(xh, xl, hh, hl,
                                                          Wh, Wl, Uh, Ul,
                                                          b, out, o_ws);
  final_kernel<<<dim3(2048), blk, 0, stream>>>(out, Cp, o_ws, out);
}

// Round 8
// 2170.333 us; speedup vs baseline: 1.0812x; 1.0812x over previous
//
#include <hip/hip_runtime.h>

// LSTM cell, B=8192, I=H=2048, fp32 in/out.
// fp16 hi/lo 3-term split GEMM on MFMA 32x32x16_f16.
// 256x256 tile, BK=64, 8 waves, 1 barrier/tile, all fragments live.
// LDS: row-major [256][64] f16 + involutive XOR swizzle ((row&7)<<4) on the
// 16B byte-col -- the r2-r6 layout with measured ZERO bank conflicts.

#define PLANE 16777216   // 8192*2048 elements per [B,H] plane
#define T_TILES 192      // 6 segments x 32 K-tiles of 64

typedef _Float16 h8_t  __attribute__((ext_vector_type(8)));
typedef _Float16 h4_t  __attribute__((ext_vector_type(4)));
typedef float    f32x16 __attribute__((ext_vector_type(16)));

#define BARRIER() do { asm volatile("" ::: "memory"); \
                       __builtin_amdgcn_s_barrier();  \
                       asm volatile("" ::: "memory"); } while (0)

__device__ __forceinline__ float fast_sigmoid(float x) {
  return 1.0f / (1.0f + __expf(-x));
}
__device__ __forceinline__ float fast_tanh(float x) {
  float e = __expf(2.0f * x);
  return 1.0f - 2.0f / (e + 1.0f);
}

// ---------------- split: fp32 -> (hi, lo) fp16 ----------------
__global__ void split_kernel(const float* __restrict__ src,
                             _Float16* __restrict__ hi,
                             _Float16* __restrict__ lo, int n) {
  int idx = (blockIdx.x * blockDim.x + threadIdx.x) * 4;
  int stride = gridDim.x * blockDim.x * 4;
  for (int i = idx; i < n; i += stride) {
    float4 v = *reinterpret_cast<const float4*>(src + i);
    _Float16 h0 = (_Float16)v.x, h1 = (_Float16)v.y,
             h2 = (_Float16)v.z, h3 = (_Float16)v.w;
    h4_t hv = {h0, h1, h2, h3};
    h4_t lv = {(_Float16)(v.x - (float)h0), (_Float16)(v.y - (float)h1),
               (_Float16)(v.z - (float)h2), (_Float16)(v.w - (float)h3)};
    *reinterpret_cast<h4_t*>(hi + i) = hv;
    *reinterpret_cast<h4_t*>(lo + i) = lv;
  }
}

// ---------------- GEMM helpers ----------------
__device__ __forceinline__ void gload_lds16(const _Float16* g, _Float16* l) {
  __builtin_amdgcn_global_load_lds(
      (const __attribute__((address_space(1))) void*)g,
      (__attribute__((address_space(3))) void*)l, 16, 0, 0);
}

__device__ __forceinline__ const _Float16* segA(int kt,
    const _Float16* xH, const _Float16* xL,
    const _Float16* hH, const _Float16* hL) {
  int s = kt >> 5;
  return s == 0 ? xH : s == 1 ? xL : s == 2 ? xH : s == 3 ? hH : s == 4 ? hL : hH;
}
__device__ __forceinline__ const _Float16* segB(int kt,
    const _Float16* wH, const _Float16* wL,
    const _Float16* uH, const _Float16* uL) {
  int s = kt >> 5;
  return s < 2 ? wH : s == 2 ? wL : s < 5 ? uH : uL;
}
#define K0OF(kt) (((kt) & 31) << 6)

__global__ __launch_bounds__(512, 2) void gemm_gates_kernel(
    const _Float16* __restrict__ xH, const _Float16* __restrict__ xL,
    const _Float16* __restrict__ hH, const _Float16* __restrict__ hL,
    const _Float16* __restrict__ wH, const _Float16* __restrict__ wL,
    const _Float16* __restrict__ uH, const _Float16* __restrict__ uL,
    const float* __restrict__ bias,
    float* __restrict__ out, _Float16* __restrict__ o_ws) {
  // row-major [256 rows][64 k] f16, XOR swizzle on 16B col: proven 0-conflict.
  __shared__ _Float16 sA[2][256 * 64];
  __shared__ _Float16 sB[2][256 * 64];

  // XCD-aware swizzle: nwg = 1024 = 8 * 128.
  const int bid = blockIdx.x;
  const int wg = (bid & 7) * 128 + (bid >> 3);
  const int tm = wg >> 5;   // 0..31 (batch rows, 256 each)
  const int tn = wg & 31;   // 0..31 (output cols, 256 each)
  const int rowA = tm * 256;
  const int rowB = tn * 256;

  const int tid = threadIdx.x;
  const int w = tid >> 6;
  const int lane = tid & 63;
  const int wr = w >> 2;    // 0..1 : wave row half (128 rows of A)
  const int wc = w & 3;     // 0..3 : wave col quarter (64 cols of B)

  // 32x32 operand read: lane covers row (lane&31), k-half (lane>>5)*8.
  const int rowRd = lane & 31;
  const int kh = lane >> 5;
  const int swl = (lane & 7) << 4;
  int co[4];   // swizzled element offset within a 64-elem row, per ks
#pragma unroll
  for (int ks = 0; ks < 4; ++ks)
    co[ks] = ((ks * 32 + kh * 16) ^ swl) >> 1;

  // Staging precompute (identical to proven r2-r6 pattern):
  // chunk c = j*512+tid -> row r = c>>3, 16B col (c&7), swizzled source.
  size_t aOff[2][2], bOff[2][2];   // [hh][j] global element offsets (k0=0)
  int ldsOff[2];                   // [j] element offset of chunk (linear dest)
#pragma unroll
  for (int j = 0; j < 2; ++j) {
    const int c = j * 512 + tid;
    const int r = c >> 3;
    const int sw = ((c & 7) << 4) ^ ((r & 7) << 4);
    ldsOff[j] = c * 8;
#pragma unroll
    for (int hh = 0; hh < 2; ++hh) {
      aOff[hh][j] = (size_t)(rowA + hh * 128 + r) * 2048 + (sw >> 1);
      bOff[hh][j] = (size_t)(rowB + hh * 128 + r) * 2048 + (sw >> 1);
    }
  }

#define STAGE_A(kt, hh) do {                                            \
    const _Float16* sg = segA((kt), xH, xL, hH, hL);                    \
    const size_t k0 = (size_t)K0OF(kt);                                 \
    _Float16* d = sA[(kt) & 1] + (hh) * 8192;                           \
    gload_lds16(sg + aOff[hh][0] + k0, d + ldsOff[0]);                  \
    gload_lds16(sg + aOff[hh][1] + k0, d + ldsOff[1]);                  \
  } while (0)
#define STAGE_B(kt, hh) do {                                            \
    const _Float16* sg = segB((kt), wH, wL, uH, uL);                    \
    const size_t k0 = (size_t)K0OF(kt);                                 \
    _Float16* d = sB[(kt) & 1] + (hh) * 8192;                           \
    gload_lds16(sg + bOff[hh][0] + k0, d + ldsOff[0]);                  \
    gload_lds16(sg + bOff[hh][1] + k0, d + ldsOff[1]);                  \
  } while (0)

  f32x16 acc[4][2];
#pragma unroll
  for (int mt = 0; mt < 4; ++mt)
#pragma unroll
    for (int nt = 0; nt < 2; ++nt)
#pragma unroll
      for (int r = 0; r < 16; ++r) acc[mt][nt][r] = 0.f;

  // Prologue: stage tile 0 fully (8 loads).
  STAGE_A(0, 0); STAGE_A(0, 1); STAGE_B(0, 0); STAGE_B(0, 1);

  h8_t aF[4][4];   // [mt][ks]  all live
  h8_t bF[2][4];   // [nt][ks]  all live

  for (int t = 0; t < T_TILES; ++t) {
    const _Float16* aP = sA[t & 1] + wr * 8192;    // 128-row half
    const _Float16* bP = sB[t & 1];

    // Tile-t stages issued >= one full tile ago; nothing else in flight =>
    // vmcnt(0) exact. BAR: residency block-wide AND all buf-reads of t-1 done.
    asm volatile("s_waitcnt vmcnt(0)" ::: "memory");
    BARRIER();

    const bool doStage = (t + 1 < T_TILES);
    if (doStage) STAGE_A(t + 1, 0);

    // ---- all 24 fragment reads (compiler interleaves lgkm waits) ----
#pragma unroll
    for (int ks = 0; ks < 4; ++ks)
#pragma unroll
      for (int mt = 0; mt < 4; ++mt)
        aF[mt][ks] = *reinterpret_cast<const h8_t*>(
            aP + (mt * 32 + rowRd) * 64 + co[ks]);
#pragma unroll
    for (int ks = 0; ks < 4; ++ks)
#pragma unroll
      for (int nt = 0; nt < 2; ++nt)
        bF[nt][ks] = *reinterpret_cast<const h8_t*>(
            bP + (wc * 64 + nt * 32 + rowRd) * 64 + co[ks]);

    if (doStage) STAGE_A(t + 1, 1);

#define DO_KS(ks) do {                                                  \
    __builtin_amdgcn_s_setprio(1);                                      \
    _Pragma("unroll")                                                   \
    for (int mt = 0; mt < 4; ++mt)                                      \
      _Pragma("unroll")                                                 \
      for (int nt = 0; nt < 2; ++nt)                                    \
        acc[mt][nt] = __builtin_amdgcn_mfma_f32_32x32x16_f16(           \
            aF[mt][ks], bF[nt][ks], acc[mt][nt], 0, 0, 0);              \
    __builtin_amdgcn_s_setprio(0);                                      \
  } while (0)

    DO_KS(0);
    if (doStage) STAGE_B(t + 1, 0);
    DO_KS(1);
    if (doStage) STAGE_B(t + 1, 1);
    DO_KS(2);
    DO_KS(3);
#undef DO_KS
  }

  // ---- epilogue: activations, fused gate writes ----
  // C/D 32x32: col = lane&31, row = (reg&3) + 8*(reg>>2) + 4*(lane>>5).
  const int gate = tn >> 3;  // 8 n-tiles per gate
  const int rBase = tm * 256 + wr * 128 + 4 * (lane >> 5);
  const int cBase = tn * 256 + wc * 64 + (lane & 31);
#pragma unroll
  for (int nt = 0; nt < 2; ++nt) {
    const int col = cBase + nt * 32;
    const int hcol = col & 2047;
    const float bv = bias[col];
#pragma unroll
    for (int mt = 0; mt < 4; ++mt) {
#pragma unroll
      for (int reg = 0; reg < 16; ++reg) {
        const int row = rBase + mt * 32 + (reg & 3) + 8 * (reg >> 2);
        float v = acc[mt][nt][reg] + bv;
        size_t oidx = (size_t)row * 2048 + hcol;
        if (gate == 0)       out[(size_t)3 * PLANE + oidx] = fast_sigmoid(v);  // f_t
        else if (gate == 1)  out[(size_t)2 * PLANE + oidx] = fast_sigmoid(v);  // i_t
        else if (gate == 2)  out[(size_t)4 * PLANE + oidx] = fast_tanh(v);     // C~_t
        else                 o_ws[oidx] = (_Float16)fast_sigmoid(v);           // o_t
      }
    }
  }
}

// ---------------- final: C_t and h_t ----------------
__global__ void final_kernel(const float* __restrict__ outr,
                             const float* __restrict__ C_prev,
                             const _Float16* __restrict__ o_ws,
                             float* __restrict__ out) {
  const float* iP = outr + (size_t)2 * PLANE;
  const float* fP = outr + (size_t)3 * PLANE;
  const float* cP = outr + (size_t)4 * PLANE;
  int idx = (blockIdx.x * blockDim.x + threadIdx.x) * 4;
  int stride = gridDim.x * blockDim.x * 4;
  for (int i = idx; i < PLANE; i += stride) {
    float4 fv = *reinterpret_cast<const float4*>(fP + i);
    float4 iv = *reinterpret_cast<const float4*>(iP + i);
    float4 cv = *reinterpret_cast<const float4*>(cP + i);
    float4 cp = *reinterpret_cast<const float4*>(C_prev + i);
    h4_t ov = *reinterpret_cast<const h4_t*>(o_ws + i);
    float4 C, H;
    C.x = fv.x * cp.x + iv.x * cv.x;
    C.y = fv.y * cp.y + iv.y * cv.y;
    C.z = fv.z * cp.z + iv.z * cv.z;
    C.w = fv.w * cp.w + iv.w * cv.w;
    H.x = (float)ov.x * fast_tanh(C.x);
    H.y = (float)ov.y * fast_tanh(C.y);
    H.z = (float)ov.z * fast_tanh(C.z);
    H.w = (float)ov.w * fast_tanh(C.w);
    *reinterpret_cast<float4*>(out + (size_t)PLANE + i) = C;  // C_t
    *reinterpret_cast<float4*>(out + i) = H;                  // h_t
  }
}

extern "C" void kernel_launch(void* const* d_in, const int* in_sizes, int n_in,
                              void* d_out, int out_size, void* d_ws, size_t ws_size,
                              hipStream_t stream) {
  const float* x  = (const float*)d_in[0];
  const float* hp = (const float*)d_in[1];
  const float* Cp = (const float*)d_in[2];
  const float* W  = (const float*)d_in[3];
  const float* U  = (const float*)d_in[4];
  const float* b  = (const float*)d_in[5];
  float* out = (float*)d_out;

  _Float16* ws = (_Float16*)d_ws;
  _Float16* xh = ws;
  _Float16* xl = xh + PLANE;
  _Float16* hh = xl + PLANE;
  _Float16* hl = hh + PLANE;
  _Float16* Wh = hl + PLANE;
  _Float16* Wl = Wh + PLANE;
  _Float16* Uh = Wl + PLANE;
  _Float16* Ul = Uh + PLANE;
  _Float16* o_ws = Ul + PLANE;  // total ws use: 9 * 32 MiB = 288 MiB

  dim3 blk(256);
  split_kernel<<<dim3(2048), blk, 0, stream>>>(x, xh, xl, PLANE);
  split_kernel<<<dim3(2048), blk, 0, stream>>>(hp, hh, hl, PLANE);
  split_kernel<<<dim3(2048), blk, 0, stream>>>(W, Wh, Wl, PLANE);
  split_kernel<<<dim3(2048), blk, 0, stream>>>(U, Uh, Ul, PLANE);
  gemm_gates_kernel<<<dim3(1024), dim3(512), 0, stream>>>(xh, xl, hh, hl,
                                                          Wh, Wl, Uh, Ul,
                                                          b, out, o_ws);
  final_kernel<<<dim3(2048), blk, 0, stream>>>(out, Cp, o_ws, out);
}

// Round 9
// 1395.853 us; speedup vs baseline: 1.6811x; 1.5548x over previous
//
#include <hip/hip_runtime.h>

// LSTM cell, B=8192, I=H=2048, fp32 in/out.
// fp16 hi/lo 2-term split GEMM (Ah*Bh + Al*Bh; dropped A_h*B_l term --
// adds ~4e-2 max error pre-activation, threshold 0.1187) on MFMA
// 16x16x32_f16. Exact r3 structure (best measured: 1860us at 3 terms):
// 256x256 tile, BK=64, 8 waves, strict 1-ahead double buffer, 2 barriers +
// counted vmcnt(2) per K-tile, stages spread across MFMA phases,
// XOR-swizzled LDS (measured 0 bank conflicts).

#define PLANE 16777216   // 8192*2048 elements per [B,H] plane
#define T_TILES 128      // 4 segments x 32 K-tiles of 64

typedef _Float16 h8_t __attribute__((ext_vector_type(8)));
typedef _Float16 h4_t __attribute__((ext_vector_type(4)));
typedef float    f32x4 __attribute__((ext_vector_type(4)));

#define BARRIER() do { asm volatile("" ::: "memory"); \
                       __builtin_amdgcn_s_barrier();  \
                       asm volatile("" ::: "memory"); } while (0)

__device__ __forceinline__ float fast_sigmoid(float x) {
  return 1.0f / (1.0f + __expf(-x));
}
__device__ __forceinline__ float fast_tanh(float x) {
  float e = __expf(2.0f * x);
  return 1.0f - 2.0f / (e + 1.0f);
}

// ---------------- splits: fp32 -> fp16 (hi[, lo]) ----------------
__global__ void split_hilo_kernel(const float* __restrict__ src,
                                  _Float16* __restrict__ hi,
                                  _Float16* __restrict__ lo, int n) {
  int idx = (blockIdx.x * blockDim.x + threadIdx.x) * 4;
  int stride = gridDim.x * blockDim.x * 4;
  for (int i = idx; i < n; i += stride) {
    float4 v = *reinterpret_cast<const float4*>(src + i);
    _Float16 h0 = (_Float16)v.x, h1 = (_Float16)v.y,
             h2 = (_Float16)v.z, h3 = (_Float16)v.w;
    h4_t hv = {h0, h1, h2, h3};
    h4_t lv = {(_Float16)(v.x - (float)h0), (_Float16)(v.y - (float)h1),
               (_Float16)(v.z - (float)h2), (_Float16)(v.w - (float)h3)};
    *reinterpret_cast<h4_t*>(hi + i) = hv;
    *reinterpret_cast<h4_t*>(lo + i) = lv;
  }
}

__global__ void split_hi_kernel(const float* __restrict__ src,
                                _Float16* __restrict__ hi, int n) {
  int idx = (blockIdx.x * blockDim.x + threadIdx.x) * 4;
  int stride = gridDim.x * blockDim.x * 4;
  for (int i = idx; i < n; i += stride) {
    float4 v = *reinterpret_cast<const float4*>(src + i);
    h4_t hv = {(_Float16)v.x, (_Float16)v.y, (_Float16)v.z, (_Float16)v.w};
    *reinterpret_cast<h4_t*>(hi + i) = hv;
  }
}

// ---------------- GEMM helpers ----------------
__device__ __forceinline__ void gload_lds16(const _Float16* g, _Float16* l) {
  __builtin_amdgcn_global_load_lds(
      (const __attribute__((address_space(1))) void*)g,
      (__attribute__((address_space(3))) void*)l, 16, 0, 0);
}

// 4 K-segments of 2048: (xh,Wh) (xl,Wh) (hh,Uh) (hl,Uh)
__device__ __forceinline__ const _Float16* segA(int kt,
    const _Float16* xH, const _Float16* xL,
    const _Float16* hH, const _Float16* hL) {
  int s = kt >> 5;
  return s == 0 ? xH : s == 1 ? xL : s == 2 ? hH : hL;
}
__device__ __forceinline__ const _Float16* segB(int kt,
    const _Float16* wH, const _Float16* uH) {
  return (kt >> 6) == 0 ? wH : uH;
}
#define K0OF(kt) (((kt) & 31) << 6)

__global__ __launch_bounds__(512, 2) void gemm_gates_kernel(
    const _Float16* __restrict__ xH, const _Float16* __restrict__ xL,
    const _Float16* __restrict__ hH, const _Float16* __restrict__ hL,
    const _Float16* __restrict__ wH, const _Float16* __restrict__ uH,
    const float* __restrict__ bias,
    float* __restrict__ out, _Float16* __restrict__ o_ws) {
  __shared__ _Float16 sA[2][256 * 64];   // 2 x 32 KiB
  __shared__ _Float16 sB[2][256 * 64];   // 2 x 32 KiB  (total 128 KiB)

  // XCD-aware swizzle: nwg = 1024 = 8 * 128.
  const int bid = blockIdx.x;
  const int wg = (bid & 7) * 128 + (bid >> 3);
  const int tm = wg >> 5;   // 0..31 (batch rows, 256 each)
  const int tn = wg & 31;   // 0..31 (output cols, 256 each)
  const int rowA = tm * 256;
  const int rowB = tn * 256;

  const int tid = threadIdx.x;
  const int w = tid >> 6;
  const int lane = tid & 63;
  const int wr = w >> 2;    // 0..1 : wave row half (128 rows)
  const int wc = w & 3;     // 0..3 : wave col quarter (64 cols)

  const int lrow = lane & 15;
  const int q = lane >> 4;
  const int swl = (lane & 7) << 4;
  // element offset within a 64-elem row for kk=0/1 (swizzled)
  const int co0 = (((0 << 6) | (q << 4)) ^ swl) >> 1;
  const int co1 = (((1 << 6) | (q << 4)) ^ swl) >> 1;

  f32x4 acc[8][4];
#pragma unroll
  for (int m = 0; m < 8; ++m)
#pragma unroll
    for (int n = 0; n < 4; ++n)
      acc[m][n] = (f32x4){0.f, 0.f, 0.f, 0.f};

  // Staging geometry (proven 0-conflict): chunk c = j*512+tid.
  size_t aOff[2][2], bOff[2][2];   // [hh][j] global element offsets (k0=0)
  int ldsOff[2];
#pragma unroll
  for (int j = 0; j < 2; ++j) {
    const int c = j * 512 + tid;
    const int r = c >> 3;
    const int sw = ((c & 7) << 4) ^ ((r & 7) << 4);
    ldsOff[j] = c * 8;
#pragma unroll
    for (int hh = 0; hh < 2; ++hh) {
      aOff[hh][j] = (size_t)(rowA + hh * 128 + r) * 2048 + (sw >> 1);
      bOff[hh][j] = (size_t)(rowB + hh * 128 + r) * 2048 + (sw >> 1);
    }
  }

#define STAGE_A(kt, hh, dst) do {                                        \
    const _Float16* sg = segA((kt), xH, xL, hH, hL);                     \
    const size_t k0 = (size_t)K0OF(kt);                                  \
    gload_lds16(sg + aOff[hh][0] + k0, (dst) + (hh) * 8192 + ldsOff[0]); \
    gload_lds16(sg + aOff[hh][1] + k0, (dst) + (hh) * 8192 + ldsOff[1]); \
  } while (0)
#define STAGE_B(kt, hh, dst) do {                                        \
    const _Float16* sg = segB((kt), wH, uH);                             \
    const size_t k0 = (size_t)K0OF(kt);                                  \
    gload_lds16(sg + bOff[hh][0] + k0, (dst) + (hh) * 8192 + ldsOff[0]); \
    gload_lds16(sg + bOff[hh][1] + k0, (dst) + (hh) * 8192 + ldsOff[1]); \
  } while (0)

  // Prologue: stage tile 0 fully (4 halves = 8 loads outstanding).
  STAGE_A(0, 0, sA[0]); STAGE_A(0, 1, sA[0]);
  STAGE_B(0, 0, sB[0]); STAGE_B(0, 1, sB[0]);

  h8_t aF[4][2];
  h8_t bN01[2][2], bN23[2][2];

  for (int t = 0; t < T_TILES; ++t) {
    const int cur = t & 1;
    const _Float16* aP = sA[cur];
    const _Float16* bP = sB[cur];
    const bool doStage = (t + 1 < T_TILES);
    const int tn1 = doStage ? t + 1 : t;
    const int k1i = K0OF(tn1);
    _Float16* dA = sA[cur ^ 1];
    _Float16* dB = sB[cur ^ 1];

    // top: issue first next-tile half BEFORE the wait (keeps vmcnt counted).
    if (doStage) STAGE_A(tn1, 0, dA);

    // wait: tile t's 4 halves retired; A0(t+1)'s 2 loads stay in flight.
    if (doStage) { asm volatile("s_waitcnt vmcnt(2)" ::: "memory"); }
    else         { asm volatile("s_waitcnt vmcnt(0)" ::: "memory"); }
    BARRIER();
    (void)k1i;

    // ---- P0: read quad0 operands; stage A1(t+1); MFMA m0-3 x n0-1 ----
#pragma unroll
    for (int nn = 0; nn < 2; ++nn) {
      const _Float16* rp = bP + (wc * 64 + nn * 16 + lrow) * 64;
      bN01[nn][0] = *reinterpret_cast<const h8_t*>(rp + co0);
      bN01[nn][1] = *reinterpret_cast<const h8_t*>(rp + co1);
    }
#pragma unroll
    for (int m = 0; m < 4; ++m) {
      const _Float16* rp = aP + (wr * 128 + m * 16 + lrow) * 64;
      aF[m][0] = *reinterpret_cast<const h8_t*>(rp + co0);
      aF[m][1] = *reinterpret_cast<const h8_t*>(rp + co1);
    }
    if (doStage) STAGE_A(tn1, 1, dA);
    __builtin_amdgcn_s_setprio(1);
#pragma unroll
    for (int mm = 0; mm < 4; ++mm)
#pragma unroll
      for (int nn = 0; nn < 2; ++nn)
#pragma unroll
        for (int kk = 0; kk < 2; ++kk)
          acc[mm][nn] = __builtin_amdgcn_mfma_f32_16x16x32_f16(
              aF[mm][kk], bN01[nn][kk], acc[mm][nn], 0, 0, 0);
    __builtin_amdgcn_s_setprio(0);

    // ---- P1: read B n2-3; stage B0(t+1); MFMA m0-3 x n2-3 ----
#pragma unroll
    for (int nn = 0; nn < 2; ++nn) {
      const _Float16* rp = bP + (wc * 64 + (2 + nn) * 16 + lrow) * 64;
      bN23[nn][0] = *reinterpret_cast<const h8_t*>(rp + co0);
      bN23[nn][1] = *reinterpret_cast<const h8_t*>(rp + co1);
    }
    if (doStage) STAGE_B(tn1, 0, dB);
    __builtin_amdgcn_s_setprio(1);
#pragma unroll
    for (int mm = 0; mm < 4; ++mm)
#pragma unroll
      for (int nn = 0; nn < 2; ++nn)
#pragma unroll
        for (int kk = 0; kk < 2; ++kk)
          acc[mm][2 + nn] = __builtin_amdgcn_mfma_f32_16x16x32_f16(
              aF[mm][kk], bN23[nn][kk], acc[mm][2 + nn], 0, 0, 0);
    __builtin_amdgcn_s_setprio(0);

    // ---- P2: read A m4-7 (reuse aF regs); stage B1(t+1); MFMA m4-7 x n0-1 ----
#pragma unroll
    for (int m = 0; m < 4; ++m) {
      const _Float16* rp = aP + (wr * 128 + (4 + m) * 16 + lrow) * 64;
      aF[m][0] = *reinterpret_cast<const h8_t*>(rp + co0);
      aF[m][1] = *reinterpret_cast<const h8_t*>(rp + co1);
    }
    if (doStage) STAGE_B(tn1, 1, dB);
    __builtin_amdgcn_s_setprio(1);
#pragma unroll
    for (int mm = 0; mm < 4; ++mm)
#pragma unroll
      for (int nn = 0; nn < 2; ++nn)
#pragma unroll
        for (int kk = 0; kk < 2; ++kk)
          acc[4 + mm][nn] = __builtin_amdgcn_mfma_f32_16x16x32_f16(
              aF[mm][kk], bN01[nn][kk], acc[4 + mm][nn], 0, 0, 0);
    __builtin_amdgcn_s_setprio(0);

    // ---- P3: MFMA m4-7 x n2-3 ----
    __builtin_amdgcn_s_setprio(1);
#pragma unroll
    for (int mm = 0; mm < 4; ++mm)
#pragma unroll
      for (int nn = 0; nn < 2; ++nn)
#pragma unroll
        for (int kk = 0; kk < 2; ++kk)
          acc[4 + mm][2 + nn] = __builtin_amdgcn_mfma_f32_16x16x32_f16(
              aF[mm][kk], bN23[nn][kk], acc[4 + mm][2 + nn], 0, 0, 0);
    __builtin_amdgcn_s_setprio(0);

    // end-of-tile: all reads of buf[cur] retired before next tile's top-stage
    // targets buf[cur] (for t+2).
    BARRIER();
  }

  // ---- epilogue: activations, fused gate writes ----
  const int gate = tn >> 3;  // 8 n-tiles per gate
  const int row0 = tm * 256 + wr * 128 + (lane >> 4) * 4;
  const int col0 = tn * 256 + wc * 64 + (lane & 15);
#pragma unroll
  for (int n = 0; n < 4; ++n) {
    const int col = col0 + n * 16;
    const int hcol = col & 2047;
    const float bv = bias[col];
#pragma unroll
    for (int m = 0; m < 8; ++m) {
      const int row = row0 + m * 16;
#pragma unroll
      for (int r = 0; r < 4; ++r) {
        float v = acc[m][n][r] + bv;
        size_t oidx = (size_t)(row + r) * 2048 + hcol;
        if (gate == 0)       out[(size_t)3 * PLANE + oidx] = fast_sigmoid(v);  // f_t
        else if (gate == 1)  out[(size_t)2 * PLANE + oidx] = fast_sigmoid(v);  // i_t
        else if (gate == 2)  out[(size_t)4 * PLANE + oidx] = fast_tanh(v);     // C~_t
        else                 o_ws[oidx] = (_Float16)fast_sigmoid(v);           // o_t
      }
    }
  }
}

// ---------------- final: C_t and h_t ----------------
__global__ void final_kernel(const float* __restrict__ outr,
                             const float* __restrict__ C_prev,
                             const _Float16* __restrict__ o_ws,
                             float* __restrict__ out) {
  const float* iP = outr + (size_t)2 * PLANE;
  const float* fP = outr + (size_t)3 * PLANE;
  const float* cP = outr + (size_t)4 * PLANE;
  int idx = (blockIdx.x * blockDim.x + threadIdx.x) * 4;
  int stride = gridDim.x * blockDim.x * 4;
  for (int i = idx; i < PLANE; i += stride) {
    float4 fv = *reinterpret_cast<const float4*>(fP + i);
    float4 iv = *reinterpret_cast<const float4*>(iP + i);
    float4 cv = *reinterpret_cast<const float4*>(cP + i);
    float4 cp = *reinterpret_cast<const float4*>(C_prev + i);
    h4_t ov = *reinterpret_cast<const h4_t*>(o_ws + i);
    float4 C, H;
    C.x = fv.x * cp.x + iv.x * cv.x;
    C.y = fv.y * cp.y + iv.y * cv.y;
    C.z = fv.z * cp.z + iv.z * cv.z;
    C.w = fv.w * cp.w + iv.w * cv.w;
    H.x = (float)ov.x * fast_tanh(C.x);
    H.y = (float)ov.y * fast_tanh(C.y);
    H.z = (float)ov.z * fast_tanh(C.z);
    H.w = (float)ov.w * fast_tanh(C.w);
    *reinterpret_cast<float4*>(out + (size_t)PLANE + i) = C;  // C_t
    *reinterpret_cast<float4*>(out + i) = H;                  // h_t
  }
}

extern "C" void kernel_launch(void* const* d_in, const int* in_sizes, int n_in,
                              void* d_out, int out_size, void* d_ws, size_t ws_size,
                              hipStream_t stream) {
  const float* x  = (const float*)d_in[0];
  const float* hp = (const float*)d_in[1];
  const float* Cp = (const float*)d_in[2];
  const float* W  = (const float*)d_in[3];
  const float* U  = (const float*)d_in[4];
  const float* b  = (const float*)d_in[5];
  float* out = (float*)d_out;

  _Float16* ws = (_Float16*)d_ws;
  _Float16* xh = ws;
  _Float16* xl = xh + PLANE;
  _Float16* hh = xl + PLANE;
  _Float16* hl = hh + PLANE;
  _Float16* Wh = hl + PLANE;
  _Float16* Uh = Wh + PLANE;
  _Float16* o_ws = Uh + PLANE;  // total ws use: 7 * 32 MiB = 224 MiB

  dim3 blk(256);
  split_hilo_kernel<<<dim3(2048), blk, 0, stream>>>(x, xh, xl, PLANE);
  split_hilo_kernel<<<dim3(2048), blk, 0, stream>>>(hp, hh, hl, PLANE);
  split_hi_kernel<<<dim3(2048), blk, 0, stream>>>(W, Wh, PLANE);
  split_hi_kernel<<<dim3(2048), blk, 0, stream>>>(U, Uh, PLANE);
  gemm_gates_kernel<<<dim3(1024), dim3(512), 0, stream>>>(xh, xl, hh, hl,
                                                          Wh, Uh,
                                                          b, out, o_ws);
  final_kernel<<<dim3(2048), blk, 0, stream>>>(out, Cp, o_ws, out);
}